// Round 19
// baseline (79.100 us; speedup 1.0000x reference)
//
#include <hip/hip_runtime.h>
#include <hip/hip_bf16.h>
#include <stdint.h>

#define B_  2
#define NF_ 2048
#define NE_ 4096
#define FD_ 128
#define HD_ 64
#define H_  4

#define LOG2E 1.44269504f
#define KH2   4.0f   // per-factor log2 offset; winner products in [2^-12, 2^13] -> f16 normal

typedef unsigned long long u64;
typedef __attribute__((ext_vector_type(4))) float f32x4;
typedef __attribute__((ext_vector_type(8))) short bf16x8;
typedef __attribute__((ext_vector_type(8))) _Float16 f16x8;
typedef __attribute__((ext_vector_type(2))) _Float16 f16x2;
typedef __attribute__((ext_vector_type(4))) unsigned uint32x4;

__device__ __forceinline__ float wave_sum64(float v) {
  #pragma unroll
  for (int m = 32; m >= 1; m >>= 1) v += __shfl_xor(v, m, 64);
  return v;
}
__device__ __forceinline__ float wave_max64(float v) {
  #pragma unroll
  for (int m = 32; m >= 1; m >>= 1) v = fmaxf(v, __shfl_xor(v, m, 64));
  return v;
}
__device__ __forceinline__ unsigned short bf16rne(float x) {
  unsigned u = __float_as_uint(x);
  return (unsigned short)((u + 0x7FFFu + ((u >> 16) & 1u)) >> 16);
}
__device__ __forceinline__ f16x2 u2h2(unsigned u) {
  union { unsigned u; f16x2 h; } c; c.u = u; return c.h;
}
__device__ __forceinline__ unsigned h22u(f16x2 h) {
  union { unsigned u; f16x2 h; } c; c.h = h; return c.u;
}
__device__ __forceinline__ unsigned short f16b(float x) {
  union { _Float16 h; unsigned short s; } c; c.h = (_Float16)x; return c.s;
}

// ---- pre: tile W into A-fragment bf16 layout + Wa = (W @ a) * log2e ----
__global__ __launch_bounds__(256) void pre_kernel(
    const float* __restrict__ Wf, const float* __restrict__ We,
    const float* __restrict__ a_fe, const float* __restrict__ a_ef,
    __hip_bfloat16* __restrict__ Wfrag, float* __restrict__ Wa)
{
  const int lane = threadIdx.x & 63, wid = threadIdx.x >> 6;
  const int dir = blockIdx.x >> 2, h = blockIdx.x & 3;
  const int cl = lane & 15, kq = lane >> 4;
  const float* W = (dir ? We : Wf) + (size_t)h * FD_ * HD_;
  __hip_bfloat16* fb = Wfrag + (size_t)(dir * 4 + h) * 8192;
  #pragma unroll
  for (int db = 0; db < 4; ++db) {
    unsigned short u[8];
    #pragma unroll
    for (int j = 0; j < 8; ++j)
      u[j] = bf16rne(W[(wid * 32 + kq * 8 + j) * HD_ + db * 16 + cl]);
    uint4 pk;
    pk.x = u[0] | ((unsigned)u[1] << 16);
    pk.y = u[2] | ((unsigned)u[3] << 16);
    pk.z = u[4] | ((unsigned)u[5] << 16);
    pk.w = u[6] | ((unsigned)u[7] << 16);
    *(uint4*)(fb + ((size_t)(wid * 4 + db) * 64 + lane) * 8) = pk;
  }
  if (wid == 0) {
    const float* a1 = a_fe + h * HD_;
    const float* a2 = a_ef + h * HD_;
    float* wa = Wa + (size_t)(dir * 4 + h) * 256;
    #pragma unroll
    for (int rep = 0; rep < 2; ++rep) {
      const int f = lane + rep * 64;
      const float* wr = W + (size_t)f * HD_;
      float s1 = 0.f, s2 = 0.f;
      #pragma unroll 8
      for (int d = 0; d < HD_; ++d) {
        s1 = fmaf(wr[d], a1[d], s1);
        s2 = fmaf(wr[d], a2[d], s2);
      }
      wa[f] = s1 * LOG2E;
      wa[128 + f] = s2 * LOG2E;
    }
  }
}

// ---- MFMA proj: 16 rows/wave; fragment-tiled f16 V + f32 row pair + f16 col E/G ----
template<int SWAP, int NN>
__device__ __forceinline__ void proj_mfma(
    const float* __restrict__ X0, const __hip_bfloat16* __restrict__ Wfrag,
    const float* __restrict__ Wa, unsigned short* __restrict__ Vp,
    float2* __restrict__ rowO, unsigned short* __restrict__ colEO,
    unsigned short* __restrict__ colGO, int job, float* __restrict__ ldsX)
{
  const int lane = threadIdx.x & 63;
  const int cl = lane & 15, kq = lane >> 4;
  const int nj = NN >> 4;
  const int nt = job & (nj - 1);
  const int bh = job / nj;
  const int n0 = nt * 16;
  const int h = bh & 3, b = bh >> 2;
  const float* x0 = X0 + ((size_t)b * NN + n0 + cl) * FD_ + kq * 8;
  const __hip_bfloat16* fb = Wfrag + (size_t)((SWAP ? 4 : 0) + h) * 8192;
  const float* wa = Wa + (size_t)((SWAP ? 4 : 0) + h) * 256 + kq * 8;

  bf16x8 wf[4][4];
  #pragma unroll
  for (int ks = 0; ks < 4; ++ks)
    #pragma unroll
    for (int db = 0; db < 4; ++db)
      wf[ks][db] = *(const bf16x8*)(fb + ((size_t)(ks * 4 + db) * 64 + lane) * 8);

  bf16x8 xf[4];
  float d1 = 0.f, d2 = 0.f;
  #pragma unroll
  for (int ks = 0; ks < 4; ++ks) {
    const f32x4 xa = *(const f32x4*)(x0 + ks * 32);
    const f32x4 xb = *(const f32x4*)(x0 + ks * 32 + 4);
    const f32x4 w1a = *(const f32x4*)(wa + ks * 32);
    const f32x4 w1b = *(const f32x4*)(wa + ks * 32 + 4);
    const f32x4 w2a = *(const f32x4*)(wa + 128 + ks * 32);
    const f32x4 w2b = *(const f32x4*)(wa + 128 + ks * 32 + 4);
    #pragma unroll
    for (int i = 0; i < 4; ++i) {
      d1 = fmaf(xa[i], w1a[i], fmaf(xb[i], w1b[i], d1));
      d2 = fmaf(xa[i], w2a[i], fmaf(xb[i], w2b[i], d2));
    }
    #pragma unroll
    for (int i = 0; i < 4; ++i) {
      xf[ks][i]     = (short)bf16rne(xa[i]);
      xf[ks][i + 4] = (short)bf16rne(xb[i]);
    }
  }
  d1 += __shfl_xor(d1, 16, 64); d1 += __shfl_xor(d1, 32, 64);
  d2 += __shfl_xor(d2, 16, 64); d2 += __shfl_xor(d2, 32, 64);

  f32x4 acc[4] = {};
  #pragma unroll
  for (int ks = 0; ks < 4; ++ks)
    #pragma unroll
    for (int db = 0; db < 4; ++db)
      acc[db] = __builtin_amdgcn_mfma_f32_16x16x32_bf16(wf[ks][db], xf[ks],
                                                        acc[db], 0, 0, 0);
  #pragma unroll
  for (int db = 0; db < 4; ++db)
    *(f32x4*)(ldsX + cl * 68 + db * 16 + kq * 4) = acc[db];
  const int mt = n0 >> 6;
  #pragma unroll
  for (int c = 0; c < 2; ++c) {
    const int nb = n0 + c * 8;
    const int ks2 = (nb >> 5) & 1, q2 = (nb >> 3) & 3;
    unsigned short u[8];
    #pragma unroll
    for (int j = 0; j < 8; ++j)
      u[j] = f16b(ldsX[(c * 8 + j) * 68 + lane]);
    uint4 pk;
    pk.x = u[0] | ((unsigned)u[1] << 16);
    pk.y = u[2] | ((unsigned)u[3] << 16);
    pk.z = u[4] | ((unsigned)u[5] << 16);
    pk.w = u[6] | ((unsigned)u[7] << 16);
    *(uint4*)(Vp + ((size_t)((mt * 8 + ks2 * 4 + (lane >> 4)) * 64
                             + q2 * 16 + (lane & 15))) * 8) = pk;
  }
  if (kq == 0) {
    const float rd = SWAP ? d2 : d1;
    const float cd = SWAP ? d1 : d2;
    float2 rp;
    rp.x = exp2f(rd - KH2);
    rp.y = exp2f(0.2f * rd - KH2);
    const size_t idxn = (size_t)bh * NN + n0 + cl;
    rowO[idxn] = rp;
    colEO[idxn] = f16b(exp2f(cd - KH2));
    colGO[idxn] = f16b(exp2f(0.2f * cd - KH2));
  }
}

// ---- bitpack: transposed bits_t[mt][n] ----
__device__ __forceinline__ void bitpack_body(
    const int* __restrict__ adj_fe, const int* __restrict__ adj_ef,
    u64* __restrict__ btfe, u64* __restrict__ btef, int id)
{
  const int lane = threadIdx.x & 63;
  const int* adj; u64* bt; int N, M, mt, g;
  if (id < 8192) {                            // fe: 64 mt x 128 g
    adj = adj_fe; bt = btfe; N = NF_; M = NE_;
    mt = id >> 7; g = id & 127;
  } else {                                    // ef: 32 mt x 256 g
    const int k = id - 8192;
    adj = adj_ef; bt = btef; N = NE_; M = NF_;
    mt = k >> 8; g = k & 255;
  }
  const int* base = adj + (size_t)(g * 16) * M + mt * 64 + lane;
  int v[16];
  #pragma unroll
  for (int r = 0; r < 16; ++r) v[r] = base[(size_t)r * M];
  u64 mine = 0;
  #pragma unroll
  for (int r = 0; r < 16; ++r) {
    u64 msk = __ballot(v[r] != 0);
    if (lane == r) mine = msk;
  }
  if (lane < 16) bt[(size_t)mt * N + g * 16 + lane] = mine;
}

// ---- fused prep ----
__global__ __launch_bounds__(256) void prep_kernel(
    const float* __restrict__ F0, const float* __restrict__ E0,
    const int* __restrict__ adj_fe, const int* __restrict__ adj_ef,
    const __hip_bfloat16* __restrict__ Wfrag, const float* __restrict__ Wa,
    unsigned short* __restrict__ Ftl, unsigned short* __restrict__ Etl,
    float2* __restrict__ rowF, unsigned short* __restrict__ colEF,
    unsigned short* __restrict__ colGF, float2* __restrict__ rowE,
    unsigned short* __restrict__ colEE, unsigned short* __restrict__ colGE,
    u64* __restrict__ btfe, u64* __restrict__ btef)
{
  __shared__ __align__(16) float ldsX[4][16 * 68];
  const int blk = blockIdx.x;
  const int wid = threadIdx.x >> 6;
  if (blk < 4096) {
    bitpack_body(adj_fe, adj_ef, btfe, btef, blk * 4 + wid);
  } else {
    const int job = (blk - 4096) * 4 + wid;   // [0, 3072)
    if (job < 1024) {
      const int bh = job >> 7;
      proj_mfma<0, NF_>(F0, Wfrag, Wa, Ftl + (size_t)bh * 32 * 4096,
                        rowF, colEF, colGF, job, ldsX[wid]);
    } else {
      const int j2 = job - 1024;
      const int bh = j2 >> 8;
      proj_mfma<1, NE_>(E0, Wfrag, Wa, Etl + (size_t)bh * 64 * 4096,
                        rowE, colEE, colGE, j2, ldsX[wid]);
    }
  }
}

// ---- attention inner loop: TWO 16-row fragments share every tile load.
// f16 packed P build; col-factor unpack shared by both fragments. ----
template<int TQ, int NN>
__device__ __forceinline__ void attn_wave2(
    const unsigned short* __restrict__ vpp, const unsigned short* __restrict__ colE,
    const unsigned short* __restrict__ colG, const u64* __restrict__ bt,
    float Ea0, float Ga0, float Ea1, float Ga1,
    int n0, int mt0, int cl, int kq,
    f32x4 (&accT0)[4], f32x4 &accS0, f32x4 (&accT1)[4], f32x4 &accS1)
{
  const int lane = threadIdx.x & 63;
  f16x8 ones;
  #pragma unroll
  for (int i = 0; i < 8; ++i) ones[i] = (_Float16)1.0f;

  const unsigned short* tb = vpp + (size_t)mt0 * 4096 + (size_t)lane * 8;
  const unsigned short* cpE = colE + mt0 * 64 + kq * 8;
  const unsigned short* cpG = colG + mt0 * 64 + kq * 8;
  const u64* bp0 = bt + (size_t)mt0 * NN + n0 + cl;
  const u64* bp1 = bp0 + 16;
  const int shk = kq * 8;
  const f16x2 Ea20 = {(_Float16)Ea0, (_Float16)Ea0};
  const f16x2 Ga20 = {(_Float16)Ga0, (_Float16)Ga0};
  const f16x2 Ea21 = {(_Float16)Ea1, (_Float16)Ea1};
  const f16x2 Ga21 = {(_Float16)Ga1, (_Float16)Ga1};

  #pragma unroll 1
  for (int t = 0; t < TQ; ++t) {
    const f16x8 vf0 = *(const f16x8*)(tb);
    const f16x8 vf1 = *(const f16x8*)(tb + 512);
    const f16x8 vf2 = *(const f16x8*)(tb + 1024);
    const f16x8 vf3 = *(const f16x8*)(tb + 1536);
    const f16x8 vf4 = *(const f16x8*)(tb + 2048);
    const f16x8 vf5 = *(const f16x8*)(tb + 2560);
    const f16x8 vf6 = *(const f16x8*)(tb + 3072);
    const f16x8 vf7 = *(const f16x8*)(tb + 3584);
    const uint32x4 ceA = *(const uint32x4*)(cpE);
    const uint32x4 ceB = *(const uint32x4*)(cpE + 32);
    const uint32x4 cgA = *(const uint32x4*)(cpG);
    const uint32x4 cgB = *(const uint32x4*)(cpG + 32);
    const u64 s0 = (*bp0) >> shk;
    const u64 s1 = (*bp1) >> shk;
    tb += 4096; cpE += 64; cpG += 64; bp0 += NN; bp1 += NN;

    uint32x4 pfu0, pfu1;
    unsigned mw0, mw1;

#define PP2(EB, GB, P) {                                                  \
      const f16x2 eb = u2h2((EB)[P]);                                     \
      const f16x2 gb = u2h2((GB)[P]);                                     \
      const f16x2 pm0 = __builtin_elementwise_max(Ea20 * eb, Ga20 * gb);  \
      const f16x2 pm1 = __builtin_elementwise_max(Ea21 * eb, Ga21 * gb);  \
      const int a0 = __builtin_amdgcn_sbfe((int)mw0, 2 * (P), 1);         \
      const int a1 = __builtin_amdgcn_sbfe((int)mw0, 2 * (P) + 1, 1);     \
      const int b0 = __builtin_amdgcn_sbfe((int)mw1, 2 * (P), 1);         \
      const int b1 = __builtin_amdgcn_sbfe((int)mw1, 2 * (P) + 1, 1);     \
      pfu0[P] = h22u(pm0) & (((unsigned)a0 & 0xFFFFu) |                   \
                             ((unsigned)a1 & 0xFFFF0000u));               \
      pfu1[P] = h22u(pm1) & (((unsigned)b0 & 0xFFFFu) |                   \
                             ((unsigned)b1 & 0xFFFF0000u));               \
    }

    // ---- ks = 0 ----
    mw0 = (unsigned)s0; mw1 = (unsigned)s1;
    PP2(ceA, cgA, 0) PP2(ceA, cgA, 1) PP2(ceA, cgA, 2) PP2(ceA, cgA, 3)
    {
      union { uint32x4 u; f16x8 h; } c0, c1; c0.u = pfu0; c1.u = pfu1;
      const f16x8 pf0 = c0.h, pf1 = c1.h;
      accS0 = __builtin_amdgcn_mfma_f32_16x16x32_f16(pf0, ones, accS0, 0, 0, 0);
      accS1 = __builtin_amdgcn_mfma_f32_16x16x32_f16(pf1, ones, accS1, 0, 0, 0);
      accT0[0] = __builtin_amdgcn_mfma_f32_16x16x32_f16(pf0, vf0, accT0[0], 0, 0, 0);
      accT1[0] = __builtin_amdgcn_mfma_f32_16x16x32_f16(pf1, vf0, accT1[0], 0, 0, 0);
      accT0[1] = __builtin_amdgcn_mfma_f32_16x16x32_f16(pf0, vf1, accT0[1], 0, 0, 0);
      accT1[1] = __builtin_amdgcn_mfma_f32_16x16x32_f16(pf1, vf1, accT1[1], 0, 0, 0);
      accT0[2] = __builtin_amdgcn_mfma_f32_16x16x32_f16(pf0, vf2, accT0[2], 0, 0, 0);
      accT1[2] = __builtin_amdgcn_mfma_f32_16x16x32_f16(pf1, vf2, accT1[2], 0, 0, 0);
      accT0[3] = __builtin_amdgcn_mfma_f32_16x16x32_f16(pf0, vf3, accT0[3], 0, 0, 0);
      accT1[3] = __builtin_amdgcn_mfma_f32_16x16x32_f16(pf1, vf3, accT1[3], 0, 0, 0);
    }
    // ---- ks = 1 ----
    mw0 = (unsigned)(s0 >> 32); mw1 = (unsigned)(s1 >> 32);
    PP2(ceB, cgB, 0) PP2(ceB, cgB, 1) PP2(ceB, cgB, 2) PP2(ceB, cgB, 3)
    {
      union { uint32x4 u; f16x8 h; } c0, c1; c0.u = pfu0; c1.u = pfu1;
      const f16x8 pf0 = c0.h, pf1 = c1.h;
      accS0 = __builtin_amdgcn_mfma_f32_16x16x32_f16(pf0, ones, accS0, 0, 0, 0);
      accS1 = __builtin_amdgcn_mfma_f32_16x16x32_f16(pf1, ones, accS1, 0, 0, 0);
      accT0[0] = __builtin_amdgcn_mfma_f32_16x16x32_f16(pf0, vf4, accT0[0], 0, 0, 0);
      accT1[0] = __builtin_amdgcn_mfma_f32_16x16x32_f16(pf1, vf4, accT1[0], 0, 0, 0);
      accT0[1] = __builtin_amdgcn_mfma_f32_16x16x32_f16(pf0, vf5, accT0[1], 0, 0, 0);
      accT1[1] = __builtin_amdgcn_mfma_f32_16x16x32_f16(pf1, vf5, accT1[1], 0, 0, 0);
      accT0[2] = __builtin_amdgcn_mfma_f32_16x16x32_f16(pf0, vf6, accT0[2], 0, 0, 0);
      accT1[2] = __builtin_amdgcn_mfma_f32_16x16x32_f16(pf1, vf6, accT1[2], 0, 0, 0);
      accT0[3] = __builtin_amdgcn_mfma_f32_16x16x32_f16(pf0, vf7, accT0[3], 0, 0, 0);
      accT1[3] = __builtin_amdgcn_mfma_f32_16x16x32_f16(pf1, vf7, accT1[3], 0, 0, 0);
    }
#undef PP2
  }
}

// ---- fused attention: block = 32 rows (2 frags), 4 waves split M.
// waves_per_eu(3,6): min=3 keeps the R17 allocator budget (clean 80-reg
// code, no spill); max=6 lifts R17's (3,3) hardware residency cap so the
// 6 blocks/CU grid can actually co-reside. ----
__global__ __launch_bounds__(256)
__attribute__((amdgpu_waves_per_eu(3, 6)))
void attn_kernel(
    const unsigned short* __restrict__ Ftl, const unsigned short* __restrict__ Etl,
    const float2* __restrict__ rowF, const unsigned short* __restrict__ colEF,
    const unsigned short* __restrict__ colGF, const float2* __restrict__ rowE,
    const unsigned short* __restrict__ colEE, const unsigned short* __restrict__ colGE,
    const u64* __restrict__ btfe, const u64* __restrict__ btef,
    float* __restrict__ out)
{
  __shared__ __align__(16) float ldsO[4 * 4 * 64 * 4];  // 16KB
  __shared__ float ldsS[4 * 16];

  const int lane = threadIdx.x & 63;
  const int wid  = threadIdx.x >> 6;
  const int cl = lane & 15, kq = lane >> 4;
  const int blk = blockIdx.x;

  int N, bh, n0;
  float* obase;
  bool relu;
  f32x4 accT0[4] = {}, accT1[4] = {};
  f32x4 accS0 = {0.f, 0.f, 0.f, 0.f}, accS1 = {0.f, 0.f, 0.f, 0.f};

  if (blk < 512) {             // fe: 8 bh x 64 rowblocks of 32
    bh = blk & 7;
    n0 = (blk >> 3) * 32;
    N = NF_;
    const float2 r0 = rowF[(size_t)bh * NF_ + n0 + cl];
    const float2 r1 = rowF[(size_t)bh * NF_ + n0 + 16 + cl];
    attn_wave2<16, NF_>(Etl + (size_t)bh * 64 * 4096,
                        colEE + (size_t)bh * NE_, colGE + (size_t)bh * NE_,
                        btfe, r0.x, r0.y, r1.x, r1.y,
                        n0, wid * 16, cl, kq, accT0, accS0, accT1, accS1);
    obase = out; relu = false;
  } else {                     // ef: 8 bh x 128 rowblocks of 32
    const int k2 = blk - 512;
    bh = k2 & 7;
    n0 = (k2 >> 3) * 32;
    N = NE_;
    const float2 r0 = rowE[(size_t)bh * NE_ + n0 + cl];
    const float2 r1 = rowE[(size_t)bh * NE_ + n0 + 16 + cl];
    attn_wave2<8, NE_>(Ftl + (size_t)bh * 32 * 4096,
                       colEF + (size_t)bh * NF_, colGF + (size_t)bh * NF_,
                       btef, r0.x, r0.y, r1.x, r1.y,
                       n0, wid * 8, cl, kq, accT0, accS0, accT1, accS1);
    obase = out + (size_t)B_ * NF_ * 256; relu = true;
  }

  const int b = bh >> 2, h = bh & 3;
  // ---- fragment 0 reduction ----
  #pragma unroll
  for (int db = 0; db < 4; ++db)
    *(f32x4*)&ldsO[((db * 4 + wid) * 64 + lane) * 4] = accT0[db];
  if (cl == 0) {
    #pragma unroll
    for (int reg = 0; reg < 4; ++reg)
      ldsS[wid * 16 + kq * 4 + reg] = accS0[reg];
  }
  __syncthreads();
  {
    f32x4 osum = {0.f, 0.f, 0.f, 0.f};
    #pragma unroll
    for (int s = 0; s < 4; ++s)
      osum += *(const f32x4*)&ldsO[((wid * 4 + s) * 64 + lane) * 4];
    float stot[4];
    #pragma unroll
    for (int reg = 0; reg < 4; ++reg) {
      stot[reg] = 0.f;
      #pragma unroll
      for (int s = 0; s < 4; ++s) stot[reg] += ldsS[s * 16 + kq * 4 + reg];
    }
    float* orow = obase + ((size_t)b * N + n0 + kq * 4) * 256 + h * HD_ + wid * 16 + cl;
    #pragma unroll
    for (int reg = 0; reg < 4; ++reg) {
      float v = osum[reg] / stot[reg];
      if (relu) v = fmaxf(v, 0.0f);
      orow[reg * 256] = v;
    }
  }
  __syncthreads();
  // ---- fragment 1 reduction ----
  #pragma unroll
  for (int db = 0; db < 4; ++db)
    *(f32x4*)&ldsO[((db * 4 + wid) * 64 + lane) * 4] = accT1[db];
  if (cl == 0) {
    #pragma unroll
    for (int reg = 0; reg < 4; ++reg)
      ldsS[wid * 16 + kq * 4 + reg] = accS1[reg];
  }
  __syncthreads();
  {
    f32x4 osum = {0.f, 0.f, 0.f, 0.f};
    #pragma unroll
    for (int s = 0; s < 4; ++s)
      osum += *(const f32x4*)&ldsO[((wid * 4 + s) * 64 + lane) * 4];
    float stot[4];
    #pragma unroll
    for (int reg = 0; reg < 4; ++reg) {
      stot[reg] = 0.f;
      #pragma unroll
      for (int s = 0; s < 4; ++s) stot[reg] += ldsS[s * 16 + kq * 4 + reg];
    }
    float* orow = obase + ((size_t)b * N + n0 + 16 + kq * 4) * 256 + h * HD_ + wid * 16 + cl;
    #pragma unroll
    for (int reg = 0; reg < 4; ++reg) {
      float v = osum[reg] / stot[reg];
      if (relu) v = fmaxf(v, 0.0f);
      orow[reg * 256] = v;
    }
  }
}

// in-place softmax over the 256-channel axis
__global__ __launch_bounds__(256) void softmax256_kernel(float* __restrict__ io)
{
  const int t = threadIdx.x;
  const int lane = t & 63, wid = t >> 6;
  float v = io[(long)blockIdx.x * 256 + t];
  __shared__ float red[8];
  float m = wave_max64(v);
  if (lane == 0) red[wid] = m;
  __syncthreads();
  m = fmaxf(fmaxf(red[0], red[1]), fmaxf(red[2], red[3]));
  float e = __expf(v - m);
  float s = wave_sum64(e);
  if (lane == 0) red[4 + wid] = s;
  __syncthreads();
  s = (red[4] + red[5]) + (red[6] + red[7]);
  io[(long)blockIdx.x * 256 + t] = e / s;
}

extern "C" void kernel_launch(void* const* d_in, const int* in_sizes, int n_in,
                              void* d_out, int out_size, void* d_ws, size_t ws_size,
                              hipStream_t stream)
{
  const float* F0   = (const float*)d_in[0];
  const float* E0   = (const float*)d_in[1];
  const int* adj_fe = (const int*)d_in[2];
  const int* adj_ef = (const int*)d_in[3];
  const float* Wf   = (const float*)d_in[4];
  const float* We   = (const float*)d_in[5];
  const float* a_fe = (const float*)d_in[6];
  const float* a_ef = (const float*)d_in[7];
  float* out = (float*)d_out;

  char* ws = (char*)d_ws;
  float2* rowF = (float2*)ws;                               // 128KB
  float2* rowE = (float2*)(ws + (128 << 10));               // 256KB
  unsigned short* colEF = (unsigned short*)(ws + (384 << 10));  // 32KB
  unsigned short* colGF = (unsigned short*)(ws + (416 << 10));  // 32KB
  unsigned short* colEE = (unsigned short*)(ws + (448 << 10));  // 64KB
  unsigned short* colGE = (unsigned short*)(ws + (512 << 10));  // 64KB
  u64* btfe = (u64*)(ws + (576 << 10));                     // 1MB
  u64* btef = btfe + (size_t)NF_ * (NE_ / 64);              // 1MB
  unsigned short* Ftl = (unsigned short*)(btef + (size_t)NE_ * (NF_ / 64)); // 2MB
  unsigned short* Etl = Ftl + (size_t)8 * 32 * 4096;        // 4MB
  __hip_bfloat16* Wfrag = (__hip_bfloat16*)(Etl + (size_t)8 * 64 * 4096);
  float* Wa = (float*)(Wfrag + (size_t)8 * 8192);

  pre_kernel<<<8, 256, 0, stream>>>(Wf, We, a_fe, a_ef, Wfrag, Wa);
  prep_kernel<<<4864, 256, 0, stream>>>(F0, E0, adj_fe, adj_ef, Wfrag, Wa,
                                        Ftl, Etl, rowF, colEF, colGF,
                                        rowE, colEE, colGE, btfe, btef);
  attn_kernel<<<1536, 256, 0, stream>>>(Ftl, Etl, rowF, colEF, colGF,
                                        rowE, colEE, colGE, btfe, btef, out);
  softmax256_kernel<<<B_ * NF_, 256, 0, stream>>>(out);
}

// Round 20
// 74.829 us; speedup vs baseline: 1.0571x; 1.0571x over previous
//
#include <hip/hip_runtime.h>
#include <hip/hip_bf16.h>
#include <stdint.h>

#define B_  2
#define NF_ 2048
#define NE_ 4096
#define FD_ 128
#define HD_ 64
#define H_  4

#define LOG2E 1.44269504f
#define KH2   4.0f   // per-factor log2 offset; winner products in [2^-12, 2^13] -> f16 normal

typedef unsigned long long u64;
typedef __attribute__((ext_vector_type(4))) float f32x4;
typedef __attribute__((ext_vector_type(8))) short bf16x8;
typedef __attribute__((ext_vector_type(8))) _Float16 f16x8;
typedef __attribute__((ext_vector_type(2))) _Float16 f16x2;
typedef __attribute__((ext_vector_type(4))) unsigned uint32x4;

__device__ __forceinline__ float wave_sum64(float v) {
  #pragma unroll
  for (int m = 32; m >= 1; m >>= 1) v += __shfl_xor(v, m, 64);
  return v;
}
__device__ __forceinline__ float wave_max64(float v) {
  #pragma unroll
  for (int m = 32; m >= 1; m >>= 1) v = fmaxf(v, __shfl_xor(v, m, 64));
  return v;
}
__device__ __forceinline__ unsigned short bf16rne(float x) {
  unsigned u = __float_as_uint(x);
  return (unsigned short)((u + 0x7FFFu + ((u >> 16) & 1u)) >> 16);
}
__device__ __forceinline__ f16x2 u2h2(unsigned u) {
  union { unsigned u; f16x2 h; } c; c.u = u; return c.h;
}
__device__ __forceinline__ unsigned h22u(f16x2 h) {
  union { unsigned u; f16x2 h; } c; c.h = h; return c.u;
}
__device__ __forceinline__ unsigned short f16b(float x) {
  union { _Float16 h; unsigned short s; } c; c.h = (_Float16)x; return c.s;
}

// ---- pre: tile W into A-fragment bf16 layout + Wa = (W @ a) * log2e ----
__global__ __launch_bounds__(256) void pre_kernel(
    const float* __restrict__ Wf, const float* __restrict__ We,
    const float* __restrict__ a_fe, const float* __restrict__ a_ef,
    __hip_bfloat16* __restrict__ Wfrag, float* __restrict__ Wa)
{
  const int lane = threadIdx.x & 63, wid = threadIdx.x >> 6;
  const int dir = blockIdx.x >> 2, h = blockIdx.x & 3;
  const int cl = lane & 15, kq = lane >> 4;
  const float* W = (dir ? We : Wf) + (size_t)h * FD_ * HD_;
  __hip_bfloat16* fb = Wfrag + (size_t)(dir * 4 + h) * 8192;
  #pragma unroll
  for (int db = 0; db < 4; ++db) {
    unsigned short u[8];
    #pragma unroll
    for (int j = 0; j < 8; ++j)
      u[j] = bf16rne(W[(wid * 32 + kq * 8 + j) * HD_ + db * 16 + cl]);
    uint4 pk;
    pk.x = u[0] | ((unsigned)u[1] << 16);
    pk.y = u[2] | ((unsigned)u[3] << 16);
    pk.z = u[4] | ((unsigned)u[5] << 16);
    pk.w = u[6] | ((unsigned)u[7] << 16);
    *(uint4*)(fb + ((size_t)(wid * 4 + db) * 64 + lane) * 8) = pk;
  }
  if (wid == 0) {
    const float* a1 = a_fe + h * HD_;
    const float* a2 = a_ef + h * HD_;
    float* wa = Wa + (size_t)(dir * 4 + h) * 256;
    #pragma unroll
    for (int rep = 0; rep < 2; ++rep) {
      const int f = lane + rep * 64;
      const float* wr = W + (size_t)f * HD_;
      float s1 = 0.f, s2 = 0.f;
      #pragma unroll 8
      for (int d = 0; d < HD_; ++d) {
        s1 = fmaf(wr[d], a1[d], s1);
        s2 = fmaf(wr[d], a2[d], s2);
      }
      wa[f] = s1 * LOG2E;
      wa[128 + f] = s2 * LOG2E;
    }
  }
}

// ---- MFMA proj: 16 rows/wave; fragment-tiled f16 V + f32 row pair + f16 col E/G ----
template<int SWAP, int NN>
__device__ __forceinline__ void proj_mfma(
    const float* __restrict__ X0, const __hip_bfloat16* __restrict__ Wfrag,
    const float* __restrict__ Wa, unsigned short* __restrict__ Vp,
    float2* __restrict__ rowO, unsigned short* __restrict__ colEO,
    unsigned short* __restrict__ colGO, int job, float* __restrict__ ldsX)
{
  const int lane = threadIdx.x & 63;
  const int cl = lane & 15, kq = lane >> 4;
  const int nj = NN >> 4;
  const int nt = job & (nj - 1);
  const int bh = job / nj;
  const int n0 = nt * 16;
  const int h = bh & 3, b = bh >> 2;
  const float* x0 = X0 + ((size_t)b * NN + n0 + cl) * FD_ + kq * 8;
  const __hip_bfloat16* fb = Wfrag + (size_t)((SWAP ? 4 : 0) + h) * 8192;
  const float* wa = Wa + (size_t)((SWAP ? 4 : 0) + h) * 256 + kq * 8;

  bf16x8 wf[4][4];
  #pragma unroll
  for (int ks = 0; ks < 4; ++ks)
    #pragma unroll
    for (int db = 0; db < 4; ++db)
      wf[ks][db] = *(const bf16x8*)(fb + ((size_t)(ks * 4 + db) * 64 + lane) * 8);

  bf16x8 xf[4];
  float d1 = 0.f, d2 = 0.f;
  #pragma unroll
  for (int ks = 0; ks < 4; ++ks) {
    const f32x4 xa = *(const f32x4*)(x0 + ks * 32);
    const f32x4 xb = *(const f32x4*)(x0 + ks * 32 + 4);
    const f32x4 w1a = *(const f32x4*)(wa + ks * 32);
    const f32x4 w1b = *(const f32x4*)(wa + ks * 32 + 4);
    const f32x4 w2a = *(const f32x4*)(wa + 128 + ks * 32);
    const f32x4 w2b = *(const f32x4*)(wa + 128 + ks * 32 + 4);
    #pragma unroll
    for (int i = 0; i < 4; ++i) {
      d1 = fmaf(xa[i], w1a[i], fmaf(xb[i], w1b[i], d1));
      d2 = fmaf(xa[i], w2a[i], fmaf(xb[i], w2b[i], d2));
    }
    #pragma unroll
    for (int i = 0; i < 4; ++i) {
      xf[ks][i]     = (short)bf16rne(xa[i]);
      xf[ks][i + 4] = (short)bf16rne(xb[i]);
    }
  }
  d1 += __shfl_xor(d1, 16, 64); d1 += __shfl_xor(d1, 32, 64);
  d2 += __shfl_xor(d2, 16, 64); d2 += __shfl_xor(d2, 32, 64);

  f32x4 acc[4] = {};
  #pragma unroll
  for (int ks = 0; ks < 4; ++ks)
    #pragma unroll
    for (int db = 0; db < 4; ++db)
      acc[db] = __builtin_amdgcn_mfma_f32_16x16x32_bf16(wf[ks][db], xf[ks],
                                                        acc[db], 0, 0, 0);
  #pragma unroll
  for (int db = 0; db < 4; ++db)
    *(f32x4*)(ldsX + cl * 68 + db * 16 + kq * 4) = acc[db];
  const int mt = n0 >> 6;
  #pragma unroll
  for (int c = 0; c < 2; ++c) {
    const int nb = n0 + c * 8;
    const int ks2 = (nb >> 5) & 1, q2 = (nb >> 3) & 3;
    unsigned short u[8];
    #pragma unroll
    for (int j = 0; j < 8; ++j)
      u[j] = f16b(ldsX[(c * 8 + j) * 68 + lane]);
    uint4 pk;
    pk.x = u[0] | ((unsigned)u[1] << 16);
    pk.y = u[2] | ((unsigned)u[3] << 16);
    pk.z = u[4] | ((unsigned)u[5] << 16);
    pk.w = u[6] | ((unsigned)u[7] << 16);
    *(uint4*)(Vp + ((size_t)((mt * 8 + ks2 * 4 + (lane >> 4)) * 64
                             + q2 * 16 + (lane & 15))) * 8) = pk;
  }
  if (kq == 0) {
    const float rd = SWAP ? d2 : d1;
    const float cd = SWAP ? d1 : d2;
    float2 rp;
    rp.x = exp2f(rd - KH2);
    rp.y = exp2f(0.2f * rd - KH2);
    const size_t idxn = (size_t)bh * NN + n0 + cl;
    rowO[idxn] = rp;
    colEO[idxn] = f16b(exp2f(cd - KH2));
    colGO[idxn] = f16b(exp2f(0.2f * cd - KH2));
  }
}

// ---- bitpack: transposed bits_t[mt][n] ----
__device__ __forceinline__ void bitpack_body(
    const int* __restrict__ adj_fe, const int* __restrict__ adj_ef,
    u64* __restrict__ btfe, u64* __restrict__ btef, int id)
{
  const int lane = threadIdx.x & 63;
  const int* adj; u64* bt; int N, M, mt, g;
  if (id < 8192) {                            // fe: 64 mt x 128 g
    adj = adj_fe; bt = btfe; N = NF_; M = NE_;
    mt = id >> 7; g = id & 127;
  } else {                                    // ef: 32 mt x 256 g
    const int k = id - 8192;
    adj = adj_ef; bt = btef; N = NE_; M = NF_;
    mt = k >> 8; g = k & 255;
  }
  const int* base = adj + (size_t)(g * 16) * M + mt * 64 + lane;
  int v[16];
  #pragma unroll
  for (int r = 0; r < 16; ++r) v[r] = base[(size_t)r * M];
  u64 mine = 0;
  #pragma unroll
  for (int r = 0; r < 16; ++r) {
    u64 msk = __ballot(v[r] != 0);
    if (lane == r) mine = msk;
  }
  if (lane < 16) bt[(size_t)mt * N + g * 16 + lane] = mine;
}

// ---- fused prep ----
__global__ __launch_bounds__(256) void prep_kernel(
    const float* __restrict__ F0, const float* __restrict__ E0,
    const int* __restrict__ adj_fe, const int* __restrict__ adj_ef,
    const __hip_bfloat16* __restrict__ Wfrag, const float* __restrict__ Wa,
    unsigned short* __restrict__ Ftl, unsigned short* __restrict__ Etl,
    float2* __restrict__ rowF, unsigned short* __restrict__ colEF,
    unsigned short* __restrict__ colGF, float2* __restrict__ rowE,
    unsigned short* __restrict__ colEE, unsigned short* __restrict__ colGE,
    u64* __restrict__ btfe, u64* __restrict__ btef)
{
  __shared__ __align__(16) float ldsX[4][16 * 68];
  const int blk = blockIdx.x;
  const int wid = threadIdx.x >> 6;
  if (blk < 4096) {
    bitpack_body(adj_fe, adj_ef, btfe, btef, blk * 4 + wid);
  } else {
    const int job = (blk - 4096) * 4 + wid;   // [0, 3072)
    if (job < 1024) {
      const int bh = job >> 7;
      proj_mfma<0, NF_>(F0, Wfrag, Wa, Ftl + (size_t)bh * 32 * 4096,
                        rowF, colEF, colGF, job, ldsX[wid]);
    } else {
      const int j2 = job - 1024;
      const int bh = j2 >> 8;
      proj_mfma<1, NE_>(E0, Wfrag, Wa, Etl + (size_t)bh * 64 * 4096,
                        rowE, colEE, colGE, j2, ldsX[wid]);
    }
  }
}

// ---- attention inner loop: TWO 16-row fragments share every tile load.
// f16 packed P build; col-factor unpack shared by both fragments. ----
template<int TQ, int NN>
__device__ __forceinline__ void attn_wave2(
    const unsigned short* __restrict__ vpp, const unsigned short* __restrict__ colE,
    const unsigned short* __restrict__ colG, const u64* __restrict__ bt,
    float Ea0, float Ga0, float Ea1, float Ga1,
    int n0, int mt0, int cl, int kq,
    f32x4 (&accT0)[4], f32x4 &accS0, f32x4 (&accT1)[4], f32x4 &accS1)
{
  const int lane = threadIdx.x & 63;
  f16x8 ones;
  #pragma unroll
  for (int i = 0; i < 8; ++i) ones[i] = (_Float16)1.0f;

  const unsigned short* tb = vpp + (size_t)mt0 * 4096 + (size_t)lane * 8;
  const unsigned short* cpE = colE + mt0 * 64 + kq * 8;
  const unsigned short* cpG = colG + mt0 * 64 + kq * 8;
  const u64* bp0 = bt + (size_t)mt0 * NN + n0 + cl;
  const u64* bp1 = bp0 + 16;
  const int shk = kq * 8;
  const f16x2 Ea20 = {(_Float16)Ea0, (_Float16)Ea0};
  const f16x2 Ga20 = {(_Float16)Ga0, (_Float16)Ga0};
  const f16x2 Ea21 = {(_Float16)Ea1, (_Float16)Ea1};
  const f16x2 Ga21 = {(_Float16)Ga1, (_Float16)Ga1};

  #pragma unroll 1
  for (int t = 0; t < TQ; ++t) {
    const f16x8 vf0 = *(const f16x8*)(tb);
    const f16x8 vf1 = *(const f16x8*)(tb + 512);
    const f16x8 vf2 = *(const f16x8*)(tb + 1024);
    const f16x8 vf3 = *(const f16x8*)(tb + 1536);
    const f16x8 vf4 = *(const f16x8*)(tb + 2048);
    const f16x8 vf5 = *(const f16x8*)(tb + 2560);
    const f16x8 vf6 = *(const f16x8*)(tb + 3072);
    const f16x8 vf7 = *(const f16x8*)(tb + 3584);
    const uint32x4 ceA = *(const uint32x4*)(cpE);
    const uint32x4 ceB = *(const uint32x4*)(cpE + 32);
    const uint32x4 cgA = *(const uint32x4*)(cpG);
    const uint32x4 cgB = *(const uint32x4*)(cpG + 32);
    const u64 s0 = (*bp0) >> shk;
    const u64 s1 = (*bp1) >> shk;
    tb += 4096; cpE += 64; cpG += 64; bp0 += NN; bp1 += NN;

    uint32x4 pfu0, pfu1;
    unsigned mw0, mw1;

#define PP2(EB, GB, P) {                                                  \
      const f16x2 eb = u2h2((EB)[P]);                                     \
      const f16x2 gb = u2h2((GB)[P]);                                     \
      const f16x2 pm0 = __builtin_elementwise_max(Ea20 * eb, Ga20 * gb);  \
      const f16x2 pm1 = __builtin_elementwise_max(Ea21 * eb, Ga21 * gb);  \
      const int a0 = __builtin_amdgcn_sbfe((int)mw0, 2 * (P), 1);         \
      const int a1 = __builtin_amdgcn_sbfe((int)mw0, 2 * (P) + 1, 1);     \
      const int b0 = __builtin_amdgcn_sbfe((int)mw1, 2 * (P), 1);         \
      const int b1 = __builtin_amdgcn_sbfe((int)mw1, 2 * (P) + 1, 1);     \
      pfu0[P] = h22u(pm0) & (((unsigned)a0 & 0xFFFFu) |                   \
                             ((unsigned)a1 & 0xFFFF0000u));               \
      pfu1[P] = h22u(pm1) & (((unsigned)b0 & 0xFFFFu) |                   \
                             ((unsigned)b1 & 0xFFFF0000u));               \
    }

    // ---- ks = 0 ----
    mw0 = (unsigned)s0; mw1 = (unsigned)s1;
    PP2(ceA, cgA, 0) PP2(ceA, cgA, 1) PP2(ceA, cgA, 2) PP2(ceA, cgA, 3)
    {
      union { uint32x4 u; f16x8 h; } c0, c1; c0.u = pfu0; c1.u = pfu1;
      const f16x8 pf0 = c0.h, pf1 = c1.h;
      accS0 = __builtin_amdgcn_mfma_f32_16x16x32_f16(pf0, ones, accS0, 0, 0, 0);
      accS1 = __builtin_amdgcn_mfma_f32_16x16x32_f16(pf1, ones, accS1, 0, 0, 0);
      accT0[0] = __builtin_amdgcn_mfma_f32_16x16x32_f16(pf0, vf0, accT0[0], 0, 0, 0);
      accT1[0] = __builtin_amdgcn_mfma_f32_16x16x32_f16(pf1, vf0, accT1[0], 0, 0, 0);
      accT0[1] = __builtin_amdgcn_mfma_f32_16x16x32_f16(pf0, vf1, accT0[1], 0, 0, 0);
      accT1[1] = __builtin_amdgcn_mfma_f32_16x16x32_f16(pf1, vf1, accT1[1], 0, 0, 0);
      accT0[2] = __builtin_amdgcn_mfma_f32_16x16x32_f16(pf0, vf2, accT0[2], 0, 0, 0);
      accT1[2] = __builtin_amdgcn_mfma_f32_16x16x32_f16(pf1, vf2, accT1[2], 0, 0, 0);
      accT0[3] = __builtin_amdgcn_mfma_f32_16x16x32_f16(pf0, vf3, accT0[3], 0, 0, 0);
      accT1[3] = __builtin_amdgcn_mfma_f32_16x16x32_f16(pf1, vf3, accT1[3], 0, 0, 0);
    }
    // ---- ks = 1 ----
    mw0 = (unsigned)(s0 >> 32); mw1 = (unsigned)(s1 >> 32);
    PP2(ceB, cgB, 0) PP2(ceB, cgB, 1) PP2(ceB, cgB, 2) PP2(ceB, cgB, 3)
    {
      union { uint32x4 u; f16x8 h; } c0, c1; c0.u = pfu0; c1.u = pfu1;
      const f16x8 pf0 = c0.h, pf1 = c1.h;
      accS0 = __builtin_amdgcn_mfma_f32_16x16x32_f16(pf0, ones, accS0, 0, 0, 0);
      accS1 = __builtin_amdgcn_mfma_f32_16x16x32_f16(pf1, ones, accS1, 0, 0, 0);
      accT0[0] = __builtin_amdgcn_mfma_f32_16x16x32_f16(pf0, vf4, accT0[0], 0, 0, 0);
      accT1[0] = __builtin_amdgcn_mfma_f32_16x16x32_f16(pf1, vf4, accT1[0], 0, 0, 0);
      accT0[1] = __builtin_amdgcn_mfma_f32_16x16x32_f16(pf0, vf5, accT0[1], 0, 0, 0);
      accT1[1] = __builtin_amdgcn_mfma_f32_16x16x32_f16(pf1, vf5, accT1[1], 0, 0, 0);
      accT0[2] = __builtin_amdgcn_mfma_f32_16x16x32_f16(pf0, vf6, accT0[2], 0, 0, 0);
      accT1[2] = __builtin_amdgcn_mfma_f32_16x16x32_f16(pf1, vf6, accT1[2], 0, 0, 0);
      accT0[3] = __builtin_amdgcn_mfma_f32_16x16x32_f16(pf0, vf7, accT0[3], 0, 0, 0);
      accT1[3] = __builtin_amdgcn_mfma_f32_16x16x32_f16(pf1, vf7, accT1[3], 0, 0, 0);
    }
#undef PP2
  }
}

// ---- fused attention: block = 32 rows (2 frags), 4 waves split M.
// amdgpu_waves_per_eu(3,3): ~168-VGPR allocator budget; live set ~80.
// Empirically the best configuration (R17: attn 44.8us, total 74.25us);
// (4,4) squeezed+spilled, (3,6) no occupancy gain + slower. ----
__global__ __launch_bounds__(256)
__attribute__((amdgpu_waves_per_eu(3, 3)))
void attn_kernel(
    const unsigned short* __restrict__ Ftl, const unsigned short* __restrict__ Etl,
    const float2* __restrict__ rowF, const unsigned short* __restrict__ colEF,
    const unsigned short* __restrict__ colGF, const float2* __restrict__ rowE,
    const unsigned short* __restrict__ colEE, const unsigned short* __restrict__ colGE,
    const u64* __restrict__ btfe, const u64* __restrict__ btef,
    float* __restrict__ out)
{
  __shared__ __align__(16) float ldsO[4 * 4 * 64 * 4];  // 16KB
  __shared__ float ldsS[4 * 16];

  const int lane = threadIdx.x & 63;
  const int wid  = threadIdx.x >> 6;
  const int cl = lane & 15, kq = lane >> 4;
  const int blk = blockIdx.x;

  int N, bh, n0;
  float* obase;
  bool relu;
  f32x4 accT0[4] = {}, accT1[4] = {};
  f32x4 accS0 = {0.f, 0.f, 0.f, 0.f}, accS1 = {0.f, 0.f, 0.f, 0.f};

  if (blk < 512) {             // fe: 8 bh x 64 rowblocks of 32
    bh = blk & 7;
    n0 = (blk >> 3) * 32;
    N = NF_;
    const float2 r0 = rowF[(size_t)bh * NF_ + n0 + cl];
    const float2 r1 = rowF[(size_t)bh * NF_ + n0 + 16 + cl];
    attn_wave2<16, NF_>(Etl + (size_t)bh * 64 * 4096,
                        colEE + (size_t)bh * NE_, colGE + (size_t)bh * NE_,
                        btfe, r0.x, r0.y, r1.x, r1.y,
                        n0, wid * 16, cl, kq, accT0, accS0, accT1, accS1);
    obase = out; relu = false;
  } else {                     // ef: 8 bh x 128 rowblocks of 32
    const int k2 = blk - 512;
    bh = k2 & 7;
    n0 = (k2 >> 3) * 32;
    N = NE_;
    const float2 r0 = rowE[(size_t)bh * NE_ + n0 + cl];
    const float2 r1 = rowE[(size_t)bh * NE_ + n0 + 16 + cl];
    attn_wave2<8, NE_>(Ftl + (size_t)bh * 32 * 4096,
                       colEF + (size_t)bh * NF_, colGF + (size_t)bh * NF_,
                       btef, r0.x, r0.y, r1.x, r1.y,
                       n0, wid * 8, cl, kq, accT0, accS0, accT1, accS1);
    obase = out + (size_t)B_ * NF_ * 256; relu = true;
  }

  const int b = bh >> 2, h = bh & 3;
  // ---- fragment 0 reduction ----
  #pragma unroll
  for (int db = 0; db < 4; ++db)
    *(f32x4*)&ldsO[((db * 4 + wid) * 64 + lane) * 4] = accT0[db];
  if (cl == 0) {
    #pragma unroll
    for (int reg = 0; reg < 4; ++reg)
      ldsS[wid * 16 + kq * 4 + reg] = accS0[reg];
  }
  __syncthreads();
  {
    f32x4 osum = {0.f, 0.f, 0.f, 0.f};
    #pragma unroll
    for (int s = 0; s < 4; ++s)
      osum += *(const f32x4*)&ldsO[((wid * 4 + s) * 64 + lane) * 4];
    float stot[4];
    #pragma unroll
    for (int reg = 0; reg < 4; ++reg) {
      stot[reg] = 0.f;
      #pragma unroll
      for (int s = 0; s < 4; ++s) stot[reg] += ldsS[s * 16 + kq * 4 + reg];
    }
    float* orow = obase + ((size_t)b * N + n0 + kq * 4) * 256 + h * HD_ + wid * 16 + cl;
    #pragma unroll
    for (int reg = 0; reg < 4; ++reg) {
      float v = osum[reg] / stot[reg];
      if (relu) v = fmaxf(v, 0.0f);
      orow[reg * 256] = v;
    }
  }
  __syncthreads();
  // ---- fragment 1 reduction ----
  #pragma unroll
  for (int db = 0; db < 4; ++db)
    *(f32x4*)&ldsO[((db * 4 + wid) * 64 + lane) * 4] = accT1[db];
  if (cl == 0) {
    #pragma unroll
    for (int reg = 0; reg < 4; ++reg)
      ldsS[wid * 16 + kq * 4 + reg] = accS1[reg];
  }
  __syncthreads();
  {
    f32x4 osum = {0.f, 0.f, 0.f, 0.f};
    #pragma unroll
    for (int s = 0; s < 4; ++s)
      osum += *(const f32x4*)&ldsO[((wid * 4 + s) * 64 + lane) * 4];
    float stot[4];
    #pragma unroll
    for (int reg = 0; reg < 4; ++reg) {
      stot[reg] = 0.f;
      #pragma unroll
      for (int s = 0; s < 4; ++s) stot[reg] += ldsS[s * 16 + kq * 4 + reg];
    }
    float* orow = obase + ((size_t)b * N + n0 + 16 + kq * 4) * 256 + h * HD_ + wid * 16 + cl;
    #pragma unroll
    for (int reg = 0; reg < 4; ++reg) {
      float v = osum[reg] / stot[reg];
      if (relu) v = fmaxf(v, 0.0f);
      orow[reg * 256] = v;
    }
  }
}

// in-place softmax over the 256-channel axis
__global__ __launch_bounds__(256) void softmax256_kernel(float* __restrict__ io)
{
  const int t = threadIdx.x;
  const int lane = t & 63, wid = t >> 6;
  float v = io[(long)blockIdx.x * 256 + t];
  __shared__ float red[8];
  float m = wave_max64(v);
  if (lane == 0) red[wid] = m;
  __syncthreads();
  m = fmaxf(fmaxf(red[0], red[1]), fmaxf(red[2], red[3]));
  float e = __expf(v - m);
  float s = wave_sum64(e);
  if (lane == 0) red[4 + wid] = s;
  __syncthreads();
  s = (red[4] + red[5]) + (red[6] + red[7]);
  io[(long)blockIdx.x * 256 + t] = e / s;
}

extern "C" void kernel_launch(void* const* d_in, const int* in_sizes, int n_in,
                              void* d_out, int out_size, void* d_ws, size_t ws_size,
                              hipStream_t stream)
{
  const float* F0   = (const float*)d_in[0];
  const float* E0   = (const float*)d_in[1];
  const int* adj_fe = (const int*)d_in[2];
  const int* adj_ef = (const int*)d_in[3];
  const float* Wf   = (const float*)d_in[4];
  const float* We   = (const float*)d_in[5];
  const float* a_fe = (const float*)d_in[6];
  const float* a_ef = (const float*)d_in[7];
  float* out = (float*)d_out;

  char* ws = (char*)d_ws;
  float2* rowF = (float2*)ws;                               // 128KB
  float2* rowE = (float2*)(ws + (128 << 10));               // 256KB
  unsigned short* colEF = (unsigned short*)(ws + (384 << 10));  // 32KB
  unsigned short* colGF = (unsigned short*)(ws + (416 << 10));  // 32KB
  unsigned short* colEE = (unsigned short*)(ws + (448 << 10));  // 64KB
  unsigned short* colGE = (unsigned short*)(ws + (512 << 10));  // 64KB
  u64* btfe = (u64*)(ws + (576 << 10));                     // 1MB
  u64* btef = btfe + (size_t)NF_ * (NE_ / 64);              // 1MB
  unsigned short* Ftl = (unsigned short*)(btef + (size_t)NE_ * (NF_ / 64)); // 2MB
  unsigned short* Etl = Ftl + (size_t)8 * 32 * 4096;        // 4MB
  __hip_bfloat16* Wfrag = (__hip_bfloat16*)(Etl + (size_t)8 * 64 * 4096);
  float* Wa = (float*)(Wfrag + (size_t)8 * 8192);

  pre_kernel<<<8, 256, 0, stream>>>(Wf, We, a_fe, a_ef, Wfrag, Wa);
  prep_kernel<<<4864, 256, 0, stream>>>(F0, E0, adj_fe, adj_ef, Wfrag, Wa,
                                        Ftl, Etl, rowF, colEF, colGF,
                                        rowE, colEE, colGE, btfe, btef);
  attn_kernel<<<1536, 256, 0, stream>>>(Ftl, Etl, rowF, colEF, colGF,
                                        rowE, colEE, colGE, btfe, btef, out);
  softmax256_kernel<<<B_ * NF_, 256, 0, stream>>>(out);
}

// Round 21
// 72.290 us; speedup vs baseline: 1.0942x; 1.0351x over previous
//
#include <hip/hip_runtime.h>
#include <hip/hip_bf16.h>
#include <stdint.h>

#define B_  2
#define NF_ 2048
#define NE_ 4096
#define FD_ 128
#define HD_ 64
#define H_  4

#define LOG2E 1.44269504f
#define KH2   4.0f   // per-factor log2 offset; winner products in [2^-12, 2^13] -> f16 normal

typedef unsigned long long u64;
typedef __attribute__((ext_vector_type(4))) float f32x4;
typedef __attribute__((ext_vector_type(8))) short bf16x8;
typedef __attribute__((ext_vector_type(8))) _Float16 f16x8;
typedef __attribute__((ext_vector_type(2))) _Float16 f16x2;
typedef __attribute__((ext_vector_type(4))) unsigned uint32x4;

__device__ __forceinline__ float wave_sum64(float v) {
  #pragma unroll
  for (int m = 32; m >= 1; m >>= 1) v += __shfl_xor(v, m, 64);
  return v;
}
__device__ __forceinline__ float wave_max64(float v) {
  #pragma unroll
  for (int m = 32; m >= 1; m >>= 1) v = fmaxf(v, __shfl_xor(v, m, 64));
  return v;
}
__device__ __forceinline__ unsigned short bf16rne(float x) {
  unsigned u = __float_as_uint(x);
  return (unsigned short)((u + 0x7FFFu + ((u >> 16) & 1u)) >> 16);
}
__device__ __forceinline__ f16x2 u2h2(unsigned u) {
  union { unsigned u; f16x2 h; } c; c.u = u; return c.h;
}
__device__ __forceinline__ unsigned h22u(f16x2 h) {
  union { unsigned u; f16x2 h; } c; c.h = h; return c.u;
}
__device__ __forceinline__ unsigned short f16b(float x) {
  union { _Float16 h; unsigned short s; } c; c.h = (_Float16)x; return c.s;
}

// ---- pre: tile W into A-fragment bf16 layout + Wa = (W @ a) * log2e ----
__global__ __launch_bounds__(256) void pre_kernel(
    const float* __restrict__ Wf, const float* __restrict__ We,
    const float* __restrict__ a_fe, const float* __restrict__ a_ef,
    __hip_bfloat16* __restrict__ Wfrag, float* __restrict__ Wa)
{
  const int lane = threadIdx.x & 63, wid = threadIdx.x >> 6;
  const int dir = blockIdx.x >> 2, h = blockIdx.x & 3;
  const int cl = lane & 15, kq = lane >> 4;
  const float* W = (dir ? We : Wf) + (size_t)h * FD_ * HD_;
  __hip_bfloat16* fb = Wfrag + (size_t)(dir * 4 + h) * 8192;
  #pragma unroll
  for (int db = 0; db < 4; ++db) {
    unsigned short u[8];
    #pragma unroll
    for (int j = 0; j < 8; ++j)
      u[j] = bf16rne(W[(wid * 32 + kq * 8 + j) * HD_ + db * 16 + cl]);
    uint4 pk;
    pk.x = u[0] | ((unsigned)u[1] << 16);
    pk.y = u[2] | ((unsigned)u[3] << 16);
    pk.z = u[4] | ((unsigned)u[5] << 16);
    pk.w = u[6] | ((unsigned)u[7] << 16);
    *(uint4*)(fb + ((size_t)(wid * 4 + db) * 64 + lane) * 8) = pk;
  }
  if (wid == 0) {
    const float* a1 = a_fe + h * HD_;
    const float* a2 = a_ef + h * HD_;
    float* wa = Wa + (size_t)(dir * 4 + h) * 256;
    #pragma unroll
    for (int rep = 0; rep < 2; ++rep) {
      const int f = lane + rep * 64;
      const float* wr = W + (size_t)f * HD_;
      float s1 = 0.f, s2 = 0.f;
      #pragma unroll 8
      for (int d = 0; d < HD_; ++d) {
        s1 = fmaf(wr[d], a1[d], s1);
        s2 = fmaf(wr[d], a2[d], s2);
      }
      wa[f] = s1 * LOG2E;
      wa[128 + f] = s2 * LOG2E;
    }
  }
}

// ---- MFMA proj: 16 rows/wave; fragment-tiled f16 V + f32 row pair + f16 col E/G ----
template<int SWAP, int NN>
__device__ __forceinline__ void proj_mfma(
    const float* __restrict__ X0, const __hip_bfloat16* __restrict__ Wfrag,
    const float* __restrict__ Wa, unsigned short* __restrict__ Vp,
    float2* __restrict__ rowO, unsigned short* __restrict__ colEO,
    unsigned short* __restrict__ colGO, int job, float* __restrict__ ldsX)
{
  const int lane = threadIdx.x & 63;
  const int cl = lane & 15, kq = lane >> 4;
  const int nj = NN >> 4;
  const int nt = job & (nj - 1);
  const int bh = job / nj;
  const int n0 = nt * 16;
  const int h = bh & 3, b = bh >> 2;
  const float* x0 = X0 + ((size_t)b * NN + n0 + cl) * FD_ + kq * 8;
  const __hip_bfloat16* fb = Wfrag + (size_t)((SWAP ? 4 : 0) + h) * 8192;
  const float* wa = Wa + (size_t)((SWAP ? 4 : 0) + h) * 256 + kq * 8;

  bf16x8 wf[4][4];
  #pragma unroll
  for (int ks = 0; ks < 4; ++ks)
    #pragma unroll
    for (int db = 0; db < 4; ++db)
      wf[ks][db] = *(const bf16x8*)(fb + ((size_t)(ks * 4 + db) * 64 + lane) * 8);

  bf16x8 xf[4];
  float d1 = 0.f, d2 = 0.f;
  #pragma unroll
  for (int ks = 0; ks < 4; ++ks) {
    const f32x4 xa = *(const f32x4*)(x0 + ks * 32);
    const f32x4 xb = *(const f32x4*)(x0 + ks * 32 + 4);
    const f32x4 w1a = *(const f32x4*)(wa + ks * 32);
    const f32x4 w1b = *(const f32x4*)(wa + ks * 32 + 4);
    const f32x4 w2a = *(const f32x4*)(wa + 128 + ks * 32);
    const f32x4 w2b = *(const f32x4*)(wa + 128 + ks * 32 + 4);
    #pragma unroll
    for (int i = 0; i < 4; ++i) {
      d1 = fmaf(xa[i], w1a[i], fmaf(xb[i], w1b[i], d1));
      d2 = fmaf(xa[i], w2a[i], fmaf(xb[i], w2b[i], d2));
    }
    #pragma unroll
    for (int i = 0; i < 4; ++i) {
      xf[ks][i]     = (short)bf16rne(xa[i]);
      xf[ks][i + 4] = (short)bf16rne(xb[i]);
    }
  }
  d1 += __shfl_xor(d1, 16, 64); d1 += __shfl_xor(d1, 32, 64);
  d2 += __shfl_xor(d2, 16, 64); d2 += __shfl_xor(d2, 32, 64);

  f32x4 acc[4] = {};
  #pragma unroll
  for (int ks = 0; ks < 4; ++ks)
    #pragma unroll
    for (int db = 0; db < 4; ++db)
      acc[db] = __builtin_amdgcn_mfma_f32_16x16x32_bf16(wf[ks][db], xf[ks],
                                                        acc[db], 0, 0, 0);
  #pragma unroll
  for (int db = 0; db < 4; ++db)
    *(f32x4*)(ldsX + cl * 68 + db * 16 + kq * 4) = acc[db];
  const int mt = n0 >> 6;
  #pragma unroll
  for (int c = 0; c < 2; ++c) {
    const int nb = n0 + c * 8;
    const int ks2 = (nb >> 5) & 1, q2 = (nb >> 3) & 3;
    unsigned short u[8];
    #pragma unroll
    for (int j = 0; j < 8; ++j)
      u[j] = f16b(ldsX[(c * 8 + j) * 68 + lane]);
    uint4 pk;
    pk.x = u[0] | ((unsigned)u[1] << 16);
    pk.y = u[2] | ((unsigned)u[3] << 16);
    pk.z = u[4] | ((unsigned)u[5] << 16);
    pk.w = u[6] | ((unsigned)u[7] << 16);
    *(uint4*)(Vp + ((size_t)((mt * 8 + ks2 * 4 + (lane >> 4)) * 64
                             + q2 * 16 + (lane & 15))) * 8) = pk;
  }
  if (kq == 0) {
    const float rd = SWAP ? d2 : d1;
    const float cd = SWAP ? d1 : d2;
    float2 rp;
    rp.x = exp2f(rd - KH2);
    rp.y = exp2f(0.2f * rd - KH2);
    const size_t idxn = (size_t)bh * NN + n0 + cl;
    rowO[idxn] = rp;
    colEO[idxn] = f16b(exp2f(cd - KH2));
    colGO[idxn] = f16b(exp2f(0.2f * cd - KH2));
  }
}

// ---- bitpack: transposed bits_t[mt][n] ----
__device__ __forceinline__ void bitpack_body(
    const int* __restrict__ adj_fe, const int* __restrict__ adj_ef,
    u64* __restrict__ btfe, u64* __restrict__ btef, int id)
{
  const int lane = threadIdx.x & 63;
  const int* adj; u64* bt; int N, M, mt, g;
  if (id < 8192) {                            // fe: 64 mt x 128 g
    adj = adj_fe; bt = btfe; N = NF_; M = NE_;
    mt = id >> 7; g = id & 127;
  } else {                                    // ef: 32 mt x 256 g
    const int k = id - 8192;
    adj = adj_ef; bt = btef; N = NE_; M = NF_;
    mt = k >> 8; g = k & 255;
  }
  const int* base = adj + (size_t)(g * 16) * M + mt * 64 + lane;
  int v[16];
  #pragma unroll
  for (int r = 0; r < 16; ++r) v[r] = base[(size_t)r * M];
  u64 mine = 0;
  #pragma unroll
  for (int r = 0; r < 16; ++r) {
    u64 msk = __ballot(v[r] != 0);
    if (lane == r) mine = msk;
  }
  if (lane < 16) bt[(size_t)mt * N + g * 16 + lane] = mine;
}

// ---- fused prep ----
__global__ __launch_bounds__(256) void prep_kernel(
    const float* __restrict__ F0, const float* __restrict__ E0,
    const int* __restrict__ adj_fe, const int* __restrict__ adj_ef,
    const __hip_bfloat16* __restrict__ Wfrag, const float* __restrict__ Wa,
    unsigned short* __restrict__ Ftl, unsigned short* __restrict__ Etl,
    float2* __restrict__ rowF, unsigned short* __restrict__ colEF,
    unsigned short* __restrict__ colGF, float2* __restrict__ rowE,
    unsigned short* __restrict__ colEE, unsigned short* __restrict__ colGE,
    u64* __restrict__ btfe, u64* __restrict__ btef)
{
  __shared__ __align__(16) float ldsX[4][16 * 68];
  const int blk = blockIdx.x;
  const int wid = threadIdx.x >> 6;
  if (blk < 4096) {
    bitpack_body(adj_fe, adj_ef, btfe, btef, blk * 4 + wid);
  } else {
    const int job = (blk - 4096) * 4 + wid;   // [0, 3072)
    if (job < 1024) {
      const int bh = job >> 7;
      proj_mfma<0, NF_>(F0, Wfrag, Wa, Ftl + (size_t)bh * 32 * 4096,
                        rowF, colEF, colGF, job, ldsX[wid]);
    } else {
      const int j2 = job - 1024;
      const int bh = j2 >> 8;
      proj_mfma<1, NE_>(E0, Wfrag, Wa, Etl + (size_t)bh * 64 * 4096,
                        rowE, colEE, colGE, j2, ldsX[wid]);
    }
  }
}

// ---- attention inner loop: FOUR 16-row fragments share every tile load.
// f16 packed P build; one col-factor unpack feeds all 4 fragments.
// Live set ~132 regs < the 168-reg (3,3) budget (R17's 2-frag was 80). ----
template<int TQ, int NN>
__device__ __forceinline__ void attn_wave4(
    const unsigned short* __restrict__ vpp, const unsigned short* __restrict__ colE,
    const unsigned short* __restrict__ colG, const u64* __restrict__ bt,
    float Ea0, float Ga0, float Ea1, float Ga1,
    float Ea2, float Ga2, float Ea3, float Ga3,
    int n0, int mt0, int cl, int kq,
    f32x4 (&accT0)[4], f32x4 &accS0, f32x4 (&accT1)[4], f32x4 &accS1,
    f32x4 (&accT2)[4], f32x4 &accS2, f32x4 (&accT3)[4], f32x4 &accS3)
{
  const int lane = threadIdx.x & 63;
  f16x8 ones;
  #pragma unroll
  for (int i = 0; i < 8; ++i) ones[i] = (_Float16)1.0f;

  const unsigned short* tb = vpp + (size_t)mt0 * 4096 + (size_t)lane * 8;
  const unsigned short* cpE = colE + mt0 * 64 + kq * 8;
  const unsigned short* cpG = colG + mt0 * 64 + kq * 8;
  const u64* bp0 = bt + (size_t)mt0 * NN + n0 + cl;
  const u64* bp1 = bp0 + 16;
  const u64* bp2 = bp0 + 32;
  const u64* bp3 = bp0 + 48;
  const int shk = kq * 8;
  const f16x2 Ea20 = {(_Float16)Ea0, (_Float16)Ea0};
  const f16x2 Ga20 = {(_Float16)Ga0, (_Float16)Ga0};
  const f16x2 Ea21 = {(_Float16)Ea1, (_Float16)Ea1};
  const f16x2 Ga21 = {(_Float16)Ga1, (_Float16)Ga1};
  const f16x2 Ea22 = {(_Float16)Ea2, (_Float16)Ea2};
  const f16x2 Ga22 = {(_Float16)Ga2, (_Float16)Ga2};
  const f16x2 Ea23 = {(_Float16)Ea3, (_Float16)Ea3};
  const f16x2 Ga23 = {(_Float16)Ga3, (_Float16)Ga3};

  #pragma unroll 1
  for (int t = 0; t < TQ; ++t) {
    const f16x8 vf0 = *(const f16x8*)(tb);
    const f16x8 vf1 = *(const f16x8*)(tb + 512);
    const f16x8 vf2 = *(const f16x8*)(tb + 1024);
    const f16x8 vf3 = *(const f16x8*)(tb + 1536);
    const f16x8 vf4 = *(const f16x8*)(tb + 2048);
    const f16x8 vf5 = *(const f16x8*)(tb + 2560);
    const f16x8 vf6 = *(const f16x8*)(tb + 3072);
    const f16x8 vf7 = *(const f16x8*)(tb + 3584);
    const uint32x4 ceA = *(const uint32x4*)(cpE);
    const uint32x4 ceB = *(const uint32x4*)(cpE + 32);
    const uint32x4 cgA = *(const uint32x4*)(cpG);
    const uint32x4 cgB = *(const uint32x4*)(cpG + 32);
    const u64 s0 = (*bp0) >> shk;
    const u64 s1 = (*bp1) >> shk;
    const u64 s2 = (*bp2) >> shk;
    const u64 s3 = (*bp3) >> shk;
    tb += 4096; cpE += 64; cpG += 64;
    bp0 += NN; bp1 += NN; bp2 += NN; bp3 += NN;

    uint32x4 pfu0, pfu1, pfu2, pfu3;
    unsigned mw0, mw1, mw2, mw3;

#define PP4(EB, GB, P) {                                                  \
      const f16x2 eb = u2h2((EB)[P]);                                     \
      const f16x2 gb = u2h2((GB)[P]);                                     \
      const f16x2 pm0 = __builtin_elementwise_max(Ea20 * eb, Ga20 * gb);  \
      const f16x2 pm1 = __builtin_elementwise_max(Ea21 * eb, Ga21 * gb);  \
      const f16x2 pm2 = __builtin_elementwise_max(Ea22 * eb, Ga22 * gb);  \
      const f16x2 pm3 = __builtin_elementwise_max(Ea23 * eb, Ga23 * gb);  \
      const int a0 = __builtin_amdgcn_sbfe((int)mw0, 2 * (P), 1);         \
      const int a1 = __builtin_amdgcn_sbfe((int)mw0, 2 * (P) + 1, 1);     \
      const int b0 = __builtin_amdgcn_sbfe((int)mw1, 2 * (P), 1);         \
      const int b1 = __builtin_amdgcn_sbfe((int)mw1, 2 * (P) + 1, 1);     \
      const int c0 = __builtin_amdgcn_sbfe((int)mw2, 2 * (P), 1);         \
      const int c1 = __builtin_amdgcn_sbfe((int)mw2, 2 * (P) + 1, 1);     \
      const int d0 = __builtin_amdgcn_sbfe((int)mw3, 2 * (P), 1);         \
      const int d1 = __builtin_amdgcn_sbfe((int)mw3, 2 * (P) + 1, 1);     \
      pfu0[P] = h22u(pm0) & (((unsigned)a0 & 0xFFFFu) |                   \
                             ((unsigned)a1 & 0xFFFF0000u));               \
      pfu1[P] = h22u(pm1) & (((unsigned)b0 & 0xFFFFu) |                   \
                             ((unsigned)b1 & 0xFFFF0000u));               \
      pfu2[P] = h22u(pm2) & (((unsigned)c0 & 0xFFFFu) |                   \
                             ((unsigned)c1 & 0xFFFF0000u));               \
      pfu3[P] = h22u(pm3) & (((unsigned)d0 & 0xFFFFu) |                   \
                             ((unsigned)d1 & 0xFFFF0000u));               \
    }

#define MMAH(VF0, VF1, VF2, VF3) {                                        \
      union { uint32x4 u; f16x8 h; } c0, c1, c2, c3;                      \
      c0.u = pfu0; c1.u = pfu1; c2.u = pfu2; c3.u = pfu3;                 \
      const f16x8 pf0 = c0.h, pf1 = c1.h, pf2 = c2.h, pf3 = c3.h;         \
      accS0 = __builtin_amdgcn_mfma_f32_16x16x32_f16(pf0, ones, accS0, 0, 0, 0); \
      accS1 = __builtin_amdgcn_mfma_f32_16x16x32_f16(pf1, ones, accS1, 0, 0, 0); \
      accS2 = __builtin_amdgcn_mfma_f32_16x16x32_f16(pf2, ones, accS2, 0, 0, 0); \
      accS3 = __builtin_amdgcn_mfma_f32_16x16x32_f16(pf3, ones, accS3, 0, 0, 0); \
      accT0[0] = __builtin_amdgcn_mfma_f32_16x16x32_f16(pf0, VF0, accT0[0], 0, 0, 0); \
      accT1[0] = __builtin_amdgcn_mfma_f32_16x16x32_f16(pf1, VF0, accT1[0], 0, 0, 0); \
      accT2[0] = __builtin_amdgcn_mfma_f32_16x16x32_f16(pf2, VF0, accT2[0], 0, 0, 0); \
      accT3[0] = __builtin_amdgcn_mfma_f32_16x16x32_f16(pf3, VF0, accT3[0], 0, 0, 0); \
      accT0[1] = __builtin_amdgcn_mfma_f32_16x16x32_f16(pf0, VF1, accT0[1], 0, 0, 0); \
      accT1[1] = __builtin_amdgcn_mfma_f32_16x16x32_f16(pf1, VF1, accT1[1], 0, 0, 0); \
      accT2[1] = __builtin_amdgcn_mfma_f32_16x16x32_f16(pf2, VF1, accT2[1], 0, 0, 0); \
      accT3[1] = __builtin_amdgcn_mfma_f32_16x16x32_f16(pf3, VF1, accT3[1], 0, 0, 0); \
      accT0[2] = __builtin_amdgcn_mfma_f32_16x16x32_f16(pf0, VF2, accT0[2], 0, 0, 0); \
      accT1[2] = __builtin_amdgcn_mfma_f32_16x16x32_f16(pf1, VF2, accT1[2], 0, 0, 0); \
      accT2[2] = __builtin_amdgcn_mfma_f32_16x16x32_f16(pf2, VF2, accT2[2], 0, 0, 0); \
      accT3[2] = __builtin_amdgcn_mfma_f32_16x16x32_f16(pf3, VF2, accT3[2], 0, 0, 0); \
      accT0[3] = __builtin_amdgcn_mfma_f32_16x16x32_f16(pf0, VF3, accT0[3], 0, 0, 0); \
      accT1[3] = __builtin_amdgcn_mfma_f32_16x16x32_f16(pf1, VF3, accT1[3], 0, 0, 0); \
      accT2[3] = __builtin_amdgcn_mfma_f32_16x16x32_f16(pf2, VF3, accT2[3], 0, 0, 0); \
      accT3[3] = __builtin_amdgcn_mfma_f32_16x16x32_f16(pf3, VF3, accT3[3], 0, 0, 0); \
    }

    // ---- ks = 0 ----
    mw0 = (unsigned)s0; mw1 = (unsigned)s1; mw2 = (unsigned)s2; mw3 = (unsigned)s3;
    PP4(ceA, cgA, 0) PP4(ceA, cgA, 1) PP4(ceA, cgA, 2) PP4(ceA, cgA, 3)
    MMAH(vf0, vf1, vf2, vf3)
    // ---- ks = 1 ----
    mw0 = (unsigned)(s0 >> 32); mw1 = (unsigned)(s1 >> 32);
    mw2 = (unsigned)(s2 >> 32); mw3 = (unsigned)(s3 >> 32);
    PP4(ceB, cgB, 0) PP4(ceB, cgB, 1) PP4(ceB, cgB, 2) PP4(ceB, cgB, 3)
    MMAH(vf4, vf5, vf6, vf7)
#undef PP4
#undef MMAH
  }
}

// ---- fused attention: block = 64 rows (4 frags), 4 waves split M.
// amdgpu_waves_per_eu(3,3): ~168-reg budget; predicted live ~132. ----
__global__ __launch_bounds__(256)
__attribute__((amdgpu_waves_per_eu(3, 3)))
void attn_kernel(
    const unsigned short* __restrict__ Ftl, const unsigned short* __restrict__ Etl,
    const float2* __restrict__ rowF, const unsigned short* __restrict__ colEF,
    const unsigned short* __restrict__ colGF, const float2* __restrict__ rowE,
    const unsigned short* __restrict__ colEE, const unsigned short* __restrict__ colGE,
    const u64* __restrict__ btfe, const u64* __restrict__ btef,
    float* __restrict__ out)
{
  __shared__ __align__(16) float ldsO[4 * 4 * 64 * 4];  // 16KB
  __shared__ float ldsS[4 * 16];

  const int lane = threadIdx.x & 63;
  const int wid  = threadIdx.x >> 6;
  const int cl = lane & 15, kq = lane >> 4;
  const int blk = blockIdx.x;

  int N, bh, n0;
  float* obase;
  bool relu;
  f32x4 accT0[4] = {}, accT1[4] = {}, accT2[4] = {}, accT3[4] = {};
  f32x4 accS0 = {0.f, 0.f, 0.f, 0.f}, accS1 = {0.f, 0.f, 0.f, 0.f};
  f32x4 accS2 = {0.f, 0.f, 0.f, 0.f}, accS3 = {0.f, 0.f, 0.f, 0.f};

  if (blk < 256) {             // fe: 8 bh x 32 rowblocks of 64
    bh = blk & 7;
    n0 = (blk >> 3) * 64;
    N = NF_;
    const float2 r0 = rowF[(size_t)bh * NF_ + n0 + cl];
    const float2 r1 = rowF[(size_t)bh * NF_ + n0 + 16 + cl];
    const float2 r2 = rowF[(size_t)bh * NF_ + n0 + 32 + cl];
    const float2 r3 = rowF[(size_t)bh * NF_ + n0 + 48 + cl];
    attn_wave4<16, NF_>(Etl + (size_t)bh * 64 * 4096,
                        colEE + (size_t)bh * NE_, colGE + (size_t)bh * NE_,
                        btfe, r0.x, r0.y, r1.x, r1.y, r2.x, r2.y, r3.x, r3.y,
                        n0, wid * 16, cl, kq,
                        accT0, accS0, accT1, accS1, accT2, accS2, accT3, accS3);
    obase = out; relu = false;
  } else {                     // ef: 8 bh x 64 rowblocks of 64
    const int k2 = blk - 256;
    bh = k2 & 7;
    n0 = (k2 >> 3) * 64;
    N = NE_;
    const float2 r0 = rowE[(size_t)bh * NE_ + n0 + cl];
    const float2 r1 = rowE[(size_t)bh * NE_ + n0 + 16 + cl];
    const float2 r2 = rowE[(size_t)bh * NE_ + n0 + 32 + cl];
    const float2 r3 = rowE[(size_t)bh * NE_ + n0 + 48 + cl];
    attn_wave4<8, NE_>(Ftl + (size_t)bh * 32 * 4096,
                       colEF + (size_t)bh * NF_, colGF + (size_t)bh * NF_,
                       btef, r0.x, r0.y, r1.x, r1.y, r2.x, r2.y, r3.x, r3.y,
                       n0, wid * 8, cl, kq,
                       accT0, accS0, accT1, accS1, accT2, accS2, accT3, accS3);
    obase = out + (size_t)B_ * NF_ * 256; relu = true;
  }

  const int b = bh >> 2, h = bh & 3;
#define REDUCE_FRAG(ACC_T, ACC_S, ROFF, FIRST) {                          \
    if (!(FIRST)) __syncthreads();                                        \
    _Pragma("unroll")                                                     \
    for (int db = 0; db < 4; ++db)                                        \
      *(f32x4*)&ldsO[((db * 4 + wid) * 64 + lane) * 4] = ACC_T[db];       \
    if (cl == 0) {                                                        \
      _Pragma("unroll")                                                   \
      for (int reg = 0; reg < 4; ++reg)                                   \
        ldsS[wid * 16 + kq * 4 + reg] = ACC_S[reg];                       \
    }                                                                     \
    __syncthreads();                                                      \
    f32x4 osum = {0.f, 0.f, 0.f, 0.f};                                    \
    _Pragma("unroll")                                                     \
    for (int s = 0; s < 4; ++s)                                           \
      osum += *(const f32x4*)&ldsO[((wid * 4 + s) * 64 + lane) * 4];      \
    float stot[4];                                                        \
    _Pragma("unroll")                                                     \
    for (int reg = 0; reg < 4; ++reg) {                                   \
      stot[reg] = 0.f;                                                    \
      _Pragma("unroll")                                                   \
      for (int s = 0; s < 4; ++s) stot[reg] += ldsS[s * 16 + kq * 4 + reg]; \
    }                                                                     \
    float* orow = obase + ((size_t)b * N + n0 + (ROFF) + kq * 4) * 256    \
                + h * HD_ + wid * 16 + cl;                                \
    _Pragma("unroll")                                                     \
    for (int reg = 0; reg < 4; ++reg) {                                   \
      float v = osum[reg] / stot[reg];                                    \
      if (relu) v = fmaxf(v, 0.0f);                                       \
      orow[reg * 256] = v;                                                \
    }                                                                     \
  }

  REDUCE_FRAG(accT0, accS0, 0, true)
  REDUCE_FRAG(accT1, accS1, 16, false)
  REDUCE_FRAG(accT2, accS2, 32, false)
  REDUCE_FRAG(accT3, accS3, 48, false)
#undef REDUCE_FRAG
}

// in-place softmax over the 256-channel axis
__global__ __launch_bounds__(256) void softmax256_kernel(float* __restrict__ io)
{
  const int t = threadIdx.x;
  const int lane = t & 63, wid = t >> 6;
  float v = io[(long)blockIdx.x * 256 + t];
  __shared__ float red[8];
  float m = wave_max64(v);
  if (lane == 0) red[wid] = m;
  __syncthreads();
  m = fmaxf(fmaxf(red[0], red[1]), fmaxf(red[2], red[3]));
  float e = __expf(v - m);
  float s = wave_sum64(e);
  if (lane == 0) red[4 + wid] = s;
  __syncthreads();
  s = (red[4] + red[5]) + (red[6] + red[7]);
  io[(long)blockIdx.x * 256 + t] = e / s;
}

extern "C" void kernel_launch(void* const* d_in, const int* in_sizes, int n_in,
                              void* d_out, int out_size, void* d_ws, size_t ws_size,
                              hipStream_t stream)
{
  const float* F0   = (const float*)d_in[0];
  const float* E0   = (const float*)d_in[1];
  const int* adj_fe = (const int*)d_in[2];
  const int* adj_ef = (const int*)d_in[3];
  const float* Wf   = (const float*)d_in[4];
  const float* We   = (const float*)d_in[5];
  const float* a_fe = (const float*)d_in[6];
  const float* a_ef = (const float*)d_in[7];
  float* out = (float*)d_out;

  char* ws = (char*)d_ws;
  float2* rowF = (float2*)ws;                               // 128KB
  float2* rowE = (float2*)(ws + (128 << 10));               // 256KB
  unsigned short* colEF = (unsigned short*)(ws + (384 << 10));  // 32KB
  unsigned short* colGF = (unsigned short*)(ws + (416 << 10));  // 32KB
  unsigned short* colEE = (unsigned short*)(ws + (448 << 10));  // 64KB
  unsigned short* colGE = (unsigned short*)(ws + (512 << 10));  // 64KB
  u64* btfe = (u64*)(ws + (576 << 10));                     // 1MB
  u64* btef = btfe + (size_t)NF_ * (NE_ / 64);              // 1MB
  unsigned short* Ftl = (unsigned short*)(btef + (size_t)NE_ * (NF_ / 64)); // 2MB
  unsigned short* Etl = Ftl + (size_t)8 * 32 * 4096;        // 4MB
  __hip_bfloat16* Wfrag = (__hip_bfloat16*)(Etl + (size_t)8 * 64 * 4096);
  float* Wa = (float*)(Wfrag + (size_t)8 * 8192);

  pre_kernel<<<8, 256, 0, stream>>>(Wf, We, a_fe, a_ef, Wfrag, Wa);
  prep_kernel<<<4864, 256, 0, stream>>>(F0, E0, adj_fe, adj_ef, Wfrag, Wa,
                                        Ftl, Etl, rowF, colEF, colGF,
                                        rowE, colEE, colGE, btfe, btef);
  attn_kernel<<<768, 256, 0, stream>>>(Ftl, Etl, rowF, colEF, colGF,
                                       rowE, colEE, colGE, btfe, btef, out);
  softmax256_kernel<<<B_ * NF_, 256, 0, stream>>>(out);
}